// Round 4
// baseline (435.969 us; speedup 1.0000x reference)
//
#include <hip/hip_runtime.h>

// ---------------------------------------------------------------------------
// DepTreeLSTM on MI355X — round 4.
// Per level: A=[emb | ht0 | ht1] (K=512) x B (640 cols) via bf16 MFMA,
// fused in-register LSTM epilogue.
// Block = 256 threads (4 waves) x MT*16 rows. Wave w owns col-tiles
// {t*4+w, t=0..NT-1} (tiles == w mod 4); since 128/16=8 == 0 mod 4, the five
// epilogue columns {h,128+h,256+h,384+h,512+h} for both of the wave's hcol
// groups are wave-local -> epilogue fully in-register.
// acc/wave = MT*NT*4 = 80 f32 (MT2) -> ~160 unified regs -> 3 waves/SIMD.
// ws: BTf bf16 fragment-packed at 0; c-state f32 [N][128] at 1MB.
// ---------------------------------------------------------------------------

typedef float f32x4 __attribute__((ext_vector_type(4)));
typedef __bf16 bf16x8 __attribute__((ext_vector_type(8)));

__device__ __forceinline__ unsigned short f2bf(float x) {
  unsigned int u = __float_as_uint(x);
  return (unsigned short)((u + 0x7fffu + ((u >> 16) & 1u)) >> 16);
}
__device__ __forceinline__ float sigf(float x) { return 1.f / (1.f + __expf(-x)); }
__device__ __forceinline__ float tanhfast(float x) {
  return 1.f - 2.f / (__expf(2.f * x) + 1.f);
}

// Pack B in fragment order: BTf[((tile*16 + ks)*64 + lane)*8 + j]
// lane = kq*16 + cl, col = tile*16+cl, k = ks*32 + kq*8 + j.
// col<384: W_iou/U_iou; col>=384: W_f (dup f0/f1) / U_f_w.
__global__ void prep_kernel(const float* __restrict__ Wi, const float* __restrict__ Ui,
                            const float* __restrict__ Wf, const float* __restrict__ Uf,
                            unsigned short* __restrict__ BTf) {
  int idx = blockIdx.x * 256 + threadIdx.x;  // 0 .. 40*16*64*8-1
  int j = idx & 7;
  int lane = (idx >> 3) & 63;
  int ks = (idx >> 9) & 15;
  int tile = idx >> 13;
  int cl = lane & 15, kq = lane >> 4;
  int col = tile * 16 + cl;
  int k = ks * 32 + kq * 8 + j;
  float v;
  if (k < 256) {
    v = (col < 384) ? Wi[k * 384 + col] : Wf[k * 128 + ((col - 384) & 127)];
  } else {
    int kk = k & 255;
    v = (col < 384) ? Ui[kk * 384 + col] : Uf[kk * 256 + (col - 384)];
  }
  BTf[idx] = f2bf(v);
}

// A-LDS fragment-order address (elements): ((mt*NKS + ks)*64 + kq*16 + r)*8 + j
template <int NKS>
__device__ __forceinline__ int a_addr(int rblk, int k) {
  int mt = rblk >> 4, r = rblk & 15;
  int ks = k >> 5, kq = (k >> 3) & 3, j = k & 7;
  return (((mt * NKS + ks) * 64 + (kq << 4) + r) << 3) + j;
}

template <bool LEAF, int MT>
__global__ __launch_bounds__(256, (LEAF ? 4 : 3)) void lvl_kernel(
    const float* __restrict__ emb, const float* __restrict__ cmask,
    const int* __restrict__ cidx, const int* __restrict__ ctype,
    const unsigned short* __restrict__ BTf,
    const float* __restrict__ b_iou, const float* __restrict__ ufb,
    const float* __restrict__ bf_,
    float* __restrict__ hout, float* __restrict__ cbuf,
    int lc, int cntm1, int offs) {
  constexpr int KD = LEAF ? 256 : 512;
  constexpr int NKS = KD / 32;          // 8 or 16
  constexpr int NT = LEAF ? 6 : 10;     // col-tiles per wave (of 24 / 40)
  constexpr int ROWS = MT * 16;
  __shared__ unsigned short Alds[ROWS * KD];

  const int tid = threadIdx.x;
  const int m0 = blockIdx.x * ROWS;

  // ---- stage emb (k 0..255) into fragment-order LDS as bf16 ----
#pragma unroll
  for (int it = 0; it < MT * 4; ++it) {
    int f = it * 256 + tid;
    int rblk = f >> 6, c4 = f & 63;
    int m = m0 + rblk;
    int g = ((m >> lc) * 63) + offs + (m & cntm1);
    const float4 v = *(const float4*)&emb[(size_t)g * 256 + c4 * 4];
    ushort4 p;
    p.x = f2bf(v.x); p.y = f2bf(v.y); p.z = f2bf(v.z); p.w = f2bf(v.w);
    *(ushort4*)&Alds[a_addr<NKS>(rblk, c4 * 4)] = p;
  }

  // ---- stage ht0 (k 256..383), ht1 (k 384..511): weighted child-h gather ----
  if (!LEAF && tid < ROWS * 4) {
    const int rblk = tid >> 2, q = tid & 3;
    int m = m0 + rblk;
    int g = ((m >> lc) * 63) + offs + (m & cntm1);
    const int ch0 = cidx[2 * g], ch1 = cidx[2 * g + 1];
    const int ty0 = ctype[2 * g], ty1 = ctype[2 * g + 1];
    const float c0 = cmask[2 * g], c1 = cmask[2 * g + 1];
    const float w00 = (ty0 == 0) ? c0 : 0.f, w01 = (ty1 == 0) ? c1 : 0.f;
    const float w10 = (ty0 == 1) ? c0 : 0.f, w11 = (ty1 == 1) ? c1 : 0.f;
#pragma unroll
    for (int jj = 0; jj < 8; ++jj) {
      int j = q * 32 + jj * 4;
      float4 a = *(const float4*)&hout[(size_t)ch0 * 128 + j];
      float4 b = *(const float4*)&hout[(size_t)ch1 * 128 + j];
      ushort4 p0, p1;
      p0.x = f2bf(w00 * a.x + w01 * b.x);
      p0.y = f2bf(w00 * a.y + w01 * b.y);
      p0.z = f2bf(w00 * a.z + w01 * b.z);
      p0.w = f2bf(w00 * a.w + w01 * b.w);
      p1.x = f2bf(w10 * a.x + w11 * b.x);
      p1.y = f2bf(w10 * a.y + w11 * b.y);
      p1.z = f2bf(w10 * a.z + w11 * b.z);
      p1.w = f2bf(w10 * a.w + w11 * b.w);
      *(ushort4*)&Alds[a_addr<NKS>(rblk, 256 + j)] = p0;
      *(ushort4*)&Alds[a_addr<NKS>(rblk, 384 + j)] = p1;
    }
  }
  __syncthreads();

  // ---- MFMA GEMM: wave w, tiles t*4+w ----
  const int lane = tid & 63;
  const int w = tid >> 6;  // wave 0..3

  const unsigned short* Bw = BTf + (size_t)w * 8192 + lane * 8;  // tile stride 8192 elem

  f32x4 acc[MT][NT];
#pragma unroll
  for (int mt = 0; mt < MT; ++mt)
#pragma unroll
    for (int t = 0; t < NT; ++t) acc[mt][t] = (f32x4){0.f, 0.f, 0.f, 0.f};

  for (int ks = 0; ks < NKS; ++ks) {
    bf16x8 b[NT];
#pragma unroll
    for (int t = 0; t < NT; ++t)
      b[t] = *(const bf16x8*)&Bw[(size_t)t * 32768 + ks * 512];
#pragma unroll
    for (int mt = 0; mt < MT; ++mt) {
      const bf16x8 a = *(const bf16x8*)&Alds[((mt * NKS + ks) * 64 + lane) << 3];
#pragma unroll
      for (int t = 0; t < NT; ++t)
        acc[mt][t] = __builtin_amdgcn_mfma_f32_16x16x32_bf16(a, b[t], acc[mt][t], 0, 0, 0);
    }
  }

  // ---- in-register epilogue ----
  // D layout: col = lane&15, row = 4*(lane>>4)+reg.
  // Wave w covers hcol_p = p*64 + w*16 + (lane&15), p in {0,1}.
  // acc[mt][2*part+p] is column part*128 + hcol_p (part: 0=i,1=o,2=u,3=f0,4=f1).
  const int cl = lane & 15;
  const int rb = (lane >> 4) << 2;
  float bi[2], bo[2], bu[2], f0b[2], f1b[2], bfv[2];
#pragma unroll
  for (int p = 0; p < 2; ++p) {
    const int hcol = p * 64 + w * 16 + cl;
    bi[p] = b_iou[hcol];
    bo[p] = b_iou[128 + hcol];
    bu[p] = b_iou[256 + hcol];
    if (!LEAF) {
      f0b[p] = ufb[hcol];
      f1b[p] = ufb[128 + hcol];
      bfv[p] = bf_[hcol];
    }
  }

#pragma unroll
  for (int mt = 0; mt < MT; ++mt) {
#pragma unroll
    for (int r = 0; r < 4; ++r) {
      const int m = m0 + (mt << 4) + rb + r;
      const int g = ((m >> lc) * 63) + offs + (m & cntm1);
      int ch0 = 0, ch1 = 0, ty0 = 0, ty1 = 0;
      float c0v = 0.f, c1v = 0.f;
      if (!LEAF) {
        ch0 = cidx[2 * g]; ch1 = cidx[2 * g + 1];
        ty0 = ctype[2 * g]; ty1 = ctype[2 * g + 1];
        c0v = cmask[2 * g]; c1v = cmask[2 * g + 1];
      }
#pragma unroll
      for (int p = 0; p < 2; ++p) {
        const int hcol = p * 64 + w * 16 + cl;
        const float iv = acc[mt][0 + p][r] + bi[p];
        const float ov = acc[mt][2 + p][r] + bo[p];
        const float uv = acc[mt][4 + p][r] + bu[p];
        float cn;
        if (LEAF) {
          cn = sigf(iv) * tanhfast(uv);
        } else {
          const float f0 = acc[mt][6 + p][r] + f0b[p];
          const float f1 = acc[mt][8 + p][r] + f1b[p];
          const float fa = (ty0 == 0) ? f0 : f1;
          const float fb = (ty1 == 0) ? f0 : f1;
          const float ft0 = sigf(fa + bfv[p]);
          const float ft1 = sigf(fb + bfv[p]);
          const float ccell = ft0 * cbuf[(size_t)ch0 * 128 + hcol] * c0v +
                              ft1 * cbuf[(size_t)ch1 * 128 + hcol] * c1v;
          cn = sigf(iv) * tanhfast(uv) + ccell;
        }
        const float hn = sigf(ov) * tanhfast(cn);
        cbuf[(size_t)g * 128 + hcol] = cn;
        hout[(size_t)g * 128 + hcol] = hn;
      }
    }
  }
}

extern "C" void kernel_launch(void* const* d_in, const int* in_sizes, int n_in,
                              void* d_out, int out_size, void* d_ws, size_t ws_size,
                              hipStream_t stream) {
  (void)in_sizes; (void)n_in; (void)out_size; (void)ws_size;
  const float* emb   = (const float*)d_in[0];
  const float* cmask = (const float*)d_in[1];
  const float* W_iou = (const float*)d_in[2];
  const float* U_iou = (const float*)d_in[3];
  const float* b_iou = (const float*)d_in[4];
  const float* W_f   = (const float*)d_in[5];
  const float* U_f_w = (const float*)d_in[6];
  const float* U_f_b = (const float*)d_in[7];
  const float* b_f   = (const float*)d_in[8];
  const int* cidx    = (const int*)d_in[9];
  const int* ctype   = (const int*)d_in[10];
  float* hout = (float*)d_out;

  unsigned short* BTf = (unsigned short*)d_ws;                // 655360 B
  float* cbuf = (float*)((char*)d_ws + (size_t)(1 << 20));    // N*128*4 = 132 MB

  prep_kernel<<<1280, 256, 0, stream>>>(W_iou, U_iou, W_f, U_f_w, BTf);

  // level 0 (leaves): M=131072, 32-row blocks
  lvl_kernel<true, 2><<<4096, 256, 0, stream>>>(emb, cmask, cidx, ctype, BTf, b_iou,
                                                U_f_b, b_f, hout, cbuf, 5, 31, 0);
  // levels 1..5
  lvl_kernel<false, 2><<<2048, 256, 0, stream>>>(emb, cmask, cidx, ctype, BTf, b_iou,
                                                 U_f_b, b_f, hout, cbuf, 4, 15, 32);
  lvl_kernel<false, 2><<<1024, 256, 0, stream>>>(emb, cmask, cidx, ctype, BTf, b_iou,
                                                 U_f_b, b_f, hout, cbuf, 3, 7, 48);
  lvl_kernel<false, 2><<<512, 256, 0, stream>>>(emb, cmask, cidx, ctype, BTf, b_iou,
                                                U_f_b, b_f, hout, cbuf, 2, 3, 56);
  lvl_kernel<false, 2><<<256, 256, 0, stream>>>(emb, cmask, cidx, ctype, BTf, b_iou,
                                                U_f_b, b_f, hout, cbuf, 1, 1, 60);
  lvl_kernel<false, 1><<<256, 256, 0, stream>>>(emb, cmask, cidx, ctype, BTf, b_iou,
                                                U_f_b, b_f, hout, cbuf, 0, 0, 62);
}

// Round 5
// 365.203 us; speedup vs baseline: 1.1938x; 1.1938x over previous
//
#include <hip/hip_runtime.h>

// ---------------------------------------------------------------------------
// DepTreeLSTM on MI355X — round 5: 2-phase pipelined GEMM (T3 template).
// Per level: A=[emb | ht0 | ht1] (K=512) x B (640 cols) via bf16 MFMA,
// fused in-register LSTM epilogue.
// Block = 512 thr (8 waves) x 64 rows (MT4). Wave w owns col-tiles {t*8+w},
// t=0..NT-1 -> single hcol = w*16+cl, parts i,o,u,f0,f1 -> in-register epilogue.
// B: per-ks 40KB slice DMA'd (global_load_lds dwordx4) into double-buffered
// LDS; one barrier per ks; stage(ks+1) overlaps MFMA(ks).
// A: fragment-order LDS image, conflict-free staging (thread owns 16B slot).
// ws: BTf bf16 fragment-packed at 0; c-state f32 [N][128] at 1MB.
// ---------------------------------------------------------------------------

typedef float f32x4 __attribute__((ext_vector_type(4)));
typedef __bf16 bf16x8 __attribute__((ext_vector_type(8)));

__device__ __forceinline__ unsigned short f2bf(float x) {
  unsigned int u = __float_as_uint(x);
  return (unsigned short)((u + 0x7fffu + ((u >> 16) & 1u)) >> 16);
}
__device__ __forceinline__ float sigf(float x) { return 1.f / (1.f + __expf(-x)); }
__device__ __forceinline__ float tanhfast(float x) {
  return 1.f - 2.f / (__expf(2.f * x) + 1.f);
}

// async 16B global->LDS
__device__ __forceinline__ void gld_lds16(const unsigned short* g, unsigned short* l) {
  __builtin_amdgcn_global_load_lds((const __attribute__((address_space(1))) void*)g,
                                   (__attribute__((address_space(3))) void*)l, 16, 0, 0);
}

// Pack B in fragment order: BTf[((tile*16 + ks)*64 + lane)*8 + j]
// lane = kq*16 + cl, col = tile*16+cl, k = ks*32 + kq*8 + j.
// col<384: W_iou/U_iou; col>=384: W_f (dup f0/f1) / U_f_w.
__global__ void prep_kernel(const float* __restrict__ Wi, const float* __restrict__ Ui,
                            const float* __restrict__ Wf, const float* __restrict__ Uf,
                            unsigned short* __restrict__ BTf) {
  int idx = blockIdx.x * 256 + threadIdx.x;  // 0 .. 40*16*64*8-1
  int j = idx & 7;
  int lane = (idx >> 3) & 63;
  int ks = (idx >> 9) & 15;
  int tile = idx >> 13;
  int cl = lane & 15, kq = lane >> 4;
  int col = tile * 16 + cl;
  int k = ks * 32 + kq * 8 + j;
  float v;
  if (k < 256) {
    v = (col < 384) ? Wi[k * 384 + col] : Wf[k * 128 + ((col - 384) & 127)];
  } else {
    int kk = k & 255;
    v = (col < 384) ? Ui[kk * 384 + col] : Uf[kk * 256 + (col - 384)];
  }
  BTf[idx] = f2bf(v);
}

// A-LDS fragment-order address (elements): ((mt*NKS + ks)*64 + kq*16 + r)*8 + j
template <int NKS>
__device__ __forceinline__ int a_addr(int rblk, int k) {
  int mt = rblk >> 4, r = rblk & 15;
  int ks = k >> 5, kq = (k >> 3) & 3, j = k & 7;
  return (((mt * NKS + ks) * 64 + (kq << 4) + r) << 3) + j;
}

template <bool LEAF>
__global__ __launch_bounds__(512, (LEAF ? 4 : 2)) void lvl_kernel(
    const float* __restrict__ emb, const float* __restrict__ cmask,
    const int* __restrict__ cidx, const int* __restrict__ ctype,
    const unsigned short* __restrict__ BTf,
    const float* __restrict__ b_iou, const float* __restrict__ ufb,
    const float* __restrict__ bf_,
    float* __restrict__ hout, float* __restrict__ cbuf,
    int lc, int cntm1, int offs) {
  constexpr int KD = LEAF ? 256 : 512;
  constexpr int NKS = KD / 32;          // 8 or 16
  constexpr int NT = LEAF ? 3 : 5;      // col-tiles per wave (24 / 40 total)
  constexpr int NTILE = NT * 8;
  constexpr int MT = 4;                 // 64 rows
  __shared__ unsigned short Alds[64 * KD];            // 32/64 KB
  __shared__ unsigned short Bb[2][NTILE * 64 * 8];    // 2x 24/40 KB

  const int tid = threadIdx.x;
  const int lane = tid & 63;
  const int w = tid >> 6;
  const int m0 = blockIdx.x * 64;

  // ---- issue B slice ks=0 DMA first (overlaps A staging) ----
  // chunk c: tile T = c*8+w; src = BTf[(T*16+ks)*512 + lane*8]; dst lane-linear.
#pragma unroll
  for (int c = 0; c < NT; ++c) {
    const int T = c * 8 + w;
    gld_lds16(&BTf[(size_t)(T * 16 + 0) * 512 + lane * 8],
              &Bb[0][(size_t)(c * 512 + w * 64) * 8]);
  }

  // ---- stage emb (k<256) conflict-free: chunk c == m-tile c; thread owns
  // LDS elems [ (c*NKS+ks_e)*512 + tid*8 .. +8 ) where ks_e=tid>>6 ----
#pragma unroll
  for (int c = 0; c < MT; ++c) {
    const int ks_e = tid >> 6;          // 0..7
    const int lq = tid & 63;
    const int r = lq & 15, kq = (lq >> 4);
    const int rblk = c * 16 + r;
    const int m = m0 + rblk;
    const int g = ((m >> lc) * 63) + offs + (m & cntm1);
    const int k0 = ks_e * 32 + kq * 8;
    const float4 v0 = *(const float4*)&emb[(size_t)g * 256 + k0];
    const float4 v1 = *(const float4*)&emb[(size_t)g * 256 + k0 + 4];
    ushort4 p0, p1;
    p0.x = f2bf(v0.x); p0.y = f2bf(v0.y); p0.z = f2bf(v0.z); p0.w = f2bf(v0.w);
    p1.x = f2bf(v1.x); p1.y = f2bf(v1.y); p1.z = f2bf(v1.z); p1.w = f2bf(v1.w);
    unsigned short* dst = &Alds[((c * NKS + ks_e) * 64 + lq) * 8];
    *(ushort4*)dst = p0;
    *(ushort4*)(dst + 4) = p1;
  }

  // ---- stage ht0 (k 256..383), ht1 (k 384..511): weighted child-h gather ----
  if (!LEAF) {
    const int rblk = tid >> 3, q = tid & 7;   // 8 threads per row, 16 cols each
    const int m = m0 + rblk;
    const int g = ((m >> lc) * 63) + offs + (m & cntm1);
    const int ch0 = cidx[2 * g], ch1 = cidx[2 * g + 1];
    const int ty0 = ctype[2 * g], ty1 = ctype[2 * g + 1];
    const float c0 = cmask[2 * g], c1 = cmask[2 * g + 1];
    const float w00 = (ty0 == 0) ? c0 : 0.f, w01 = (ty1 == 0) ? c1 : 0.f;
    const float w10 = (ty0 == 1) ? c0 : 0.f, w11 = (ty1 == 1) ? c1 : 0.f;
#pragma unroll
    for (int jj = 0; jj < 4; ++jj) {
      const int j = q * 16 + jj * 4;
      float4 a = *(const float4*)&hout[(size_t)ch0 * 128 + j];
      float4 b = *(const float4*)&hout[(size_t)ch1 * 128 + j];
      ushort4 p0, p1;
      p0.x = f2bf(w00 * a.x + w01 * b.x);
      p0.y = f2bf(w00 * a.y + w01 * b.y);
      p0.z = f2bf(w00 * a.z + w01 * b.z);
      p0.w = f2bf(w00 * a.w + w01 * b.w);
      p1.x = f2bf(w10 * a.x + w11 * b.x);
      p1.y = f2bf(w10 * a.y + w11 * b.y);
      p1.z = f2bf(w10 * a.z + w11 * b.z);
      p1.w = f2bf(w10 * a.w + w11 * b.w);
      *(ushort4*)&Alds[a_addr<NKS>(rblk, 256 + j)] = p0;
      *(ushort4*)&Alds[a_addr<NKS>(rblk, 384 + j)] = p1;
    }
  }
  __syncthreads();   // drains DMA(ks=0) + LDS writes

  // ---- 2-phase pipelined MFMA loop ----
  f32x4 acc[MT][NT];
#pragma unroll
  for (int mt = 0; mt < MT; ++mt)
#pragma unroll
    for (int t = 0; t < NT; ++t) acc[mt][t] = (f32x4){0.f, 0.f, 0.f, 0.f};

  int cur = 0;
  for (int ks = 0; ks < NKS; ++ks) {
    // issue next-slice DMA before compute
    if (ks + 1 < NKS) {
#pragma unroll
      for (int c = 0; c < NT; ++c) {
        const int T = c * 8 + w;
        gld_lds16(&BTf[(size_t)(T * 16 + ks + 1) * 512 + lane * 8],
                  &Bb[cur ^ 1][(size_t)(c * 512 + w * 64) * 8]);
      }
    }
    bf16x8 b[NT];
#pragma unroll
    for (int t = 0; t < NT; ++t)
      b[t] = *(const bf16x8*)&Bb[cur][(size_t)((t * 8 + w) * 64 + lane) * 8];
#pragma unroll
    for (int mt = 0; mt < MT; ++mt) {
      const bf16x8 a = *(const bf16x8*)&Alds[((mt * NKS + ks) * 64 + lane) << 3];
#pragma unroll
      for (int t = 0; t < NT; ++t)
        acc[mt][t] = __builtin_amdgcn_mfma_f32_16x16x32_bf16(a, b[t], acc[mt][t], 0, 0, 0);
    }
    __syncthreads();   // everyone done with Bb[cur]; DMA into Bb[cur^1] drained
    cur ^= 1;
  }

  // ---- in-register epilogue: wave w handles hcol = w*16 + cl ----
  // D layout: col = lane&15, row = 4*(lane>>4)+reg; part t: i,o,u,f0,f1.
  const int cl = lane & 15;
  const int rb = (lane >> 4) << 2;
  const int hcol = w * 16 + cl;
  const float bi = b_iou[hcol];
  const float bo = b_iou[128 + hcol];
  const float bu = b_iou[256 + hcol];
  float f0b = 0.f, f1b = 0.f, bfv = 0.f;
  if (!LEAF) { f0b = ufb[hcol]; f1b = ufb[128 + hcol]; bfv = bf_[hcol]; }

#pragma unroll
  for (int mt = 0; mt < MT; ++mt) {
#pragma unroll
    for (int r = 0; r < 4; ++r) {
      const int m = m0 + (mt << 4) + rb + r;
      const int g = ((m >> lc) * 63) + offs + (m & cntm1);
      const float iv = acc[mt][0][r] + bi;
      const float ov = acc[mt][1][r] + bo;
      const float uv = acc[mt][2][r] + bu;
      float cn;
      if (LEAF) {
        cn = sigf(iv) * tanhfast(uv);
      } else {
        const int ch0 = cidx[2 * g], ch1 = cidx[2 * g + 1];
        const int ty0 = ctype[2 * g], ty1 = ctype[2 * g + 1];
        const float c0v = cmask[2 * g], c1v = cmask[2 * g + 1];
        const float f0 = acc[mt][3][r] + f0b;
        const float f1 = acc[mt][4][r] + f1b;
        const float fa = (ty0 == 0) ? f0 : f1;
        const float fb = (ty1 == 0) ? f0 : f1;
        const float ft0 = sigf(fa + bfv);
        const float ft1 = sigf(fb + bfv);
        const float ccell = ft0 * cbuf[(size_t)ch0 * 128 + hcol] * c0v +
                            ft1 * cbuf[(size_t)ch1 * 128 + hcol] * c1v;
        cn = sigf(iv) * tanhfast(uv) + ccell;
      }
      const float hn = sigf(ov) * tanhfast(cn);
      cbuf[(size_t)g * 128 + hcol] = cn;
      hout[(size_t)g * 128 + hcol] = hn;
    }
  }
}

extern "C" void kernel_launch(void* const* d_in, const int* in_sizes, int n_in,
                              void* d_out, int out_size, void* d_ws, size_t ws_size,
                              hipStream_t stream) {
  (void)in_sizes; (void)n_in; (void)out_size; (void)ws_size;
  const float* emb   = (const float*)d_in[0];
  const float* cmask = (const float*)d_in[1];
  const float* W_iou = (const float*)d_in[2];
  const float* U_iou = (const float*)d_in[3];
  const float* b_iou = (const float*)d_in[4];
  const float* W_f   = (const float*)d_in[5];
  const float* U_f_w = (const float*)d_in[6];
  const float* U_f_b = (const float*)d_in[7];
  const float* b_f   = (const float*)d_in[8];
  const int* cidx    = (const int*)d_in[9];
  const int* ctype   = (const int*)d_in[10];
  float* hout = (float*)d_out;

  unsigned short* BTf = (unsigned short*)d_ws;                // 655360 B
  float* cbuf = (float*)((char*)d_ws + (size_t)(1 << 20));    // N*128*4 = 132 MB

  prep_kernel<<<1280, 256, 0, stream>>>(W_iou, U_iou, W_f, U_f_w, BTf);

  // level 0 (leaves): M=131072, 64-row blocks
  lvl_kernel<true><<<2048, 512, 0, stream>>>(emb, cmask, cidx, ctype, BTf, b_iou,
                                             U_f_b, b_f, hout, cbuf, 5, 31, 0);
  // levels 1..5
  lvl_kernel<false><<<1024, 512, 0, stream>>>(emb, cmask, cidx, ctype, BTf, b_iou,
                                              U_f_b, b_f, hout, cbuf, 4, 15, 32);
  lvl_kernel<false><<<512, 512, 0, stream>>>(emb, cmask, cidx, ctype, BTf, b_iou,
                                             U_f_b, b_f, hout, cbuf, 3, 7, 48);
  lvl_kernel<false><<<256, 512, 0, stream>>>(emb, cmask, cidx, ctype, BTf, b_iou,
                                             U_f_b, b_f, hout, cbuf, 2, 3, 56);
  lvl_kernel<false><<<128, 512, 0, stream>>>(emb, cmask, cidx, ctype, BTf, b_iou,
                                             U_f_b, b_f, hout, cbuf, 1, 1, 60);
  lvl_kernel<false><<<64, 512, 0, stream>>>(emb, cmask, cidx, ctype, BTf, b_iou,
                                            U_f_b, b_f, hout, cbuf, 0, 0, 62);
}